// Round 8
// baseline (144.708 us; speedup 1.0000x reference)
//
#include <hip/hip_runtime.h>
#include <math.h>

#define BLOCK 256
#define RB 32            // rows per block -> grid = 512
#define BD 64            // K-chunk
#define NE 64
#define DDIM 2048
#define TOPK 8
#define NCHUNK (DDIM / BD)   // 32

typedef float __attribute__((ext_vector_type(4))) f32x4;

__global__ __launch_bounds__(BLOCK, 2) void gate_kernel(
    const float* __restrict__ x,      // [NR, D]
    const float* __restrict__ w,      // [E, D]
    const float* __restrict__ bias,   // [E]
    float* __restrict__ out_w,        // [NR, K]
    float* __restrict__ out_i)        // [NR, K] indices as float
{
    const int t    = threadIdx.x;
    const int lane = t & 63;
    const int wid  = t >> 6;          // wave id: owns rows wid*8 .. wid*8+7
    const int kc   = lane & 15;       // col group: cols 4kc..4kc+3 of chunk
    const int kh   = lane >> 4;       // expert group: experts kh*16 .. +15
    const int row0 = blockIdx.x * RB;

    float acc[8][16];
#pragma unroll
    for (int r = 0; r < 8; ++r)
#pragma unroll
        for (int j = 0; j < 16; ++j) acc[r][j] = 0.f;

    // per-thread base pointers (64-bit math done once)
    const float* xb = x + (size_t)(row0 + wid * 8) * DDIM + kc * 4;
    const float* wb = w + (size_t)(kh * 16) * DDIM + kc * 4;

    // main loop: no LDS, no barriers. w chunk (16KB) is L1-resident (shared by
    // all 8 waves on the CU); x streams from HBM. 24 independent dwordx4 loads
    // per chunk -> compiler pipelines across iterations via vmcnt.
    for (int c = 0; c < NCHUNK; ++c) {
        const int d0 = c * BD;

        f32x4 xv[8];
#pragma unroll
        for (int r = 0; r < 8; ++r)
            xv[r] = *(const f32x4*)(xb + (size_t)r * DDIM + d0);

        f32x4 wv[16];
#pragma unroll
        for (int j = 0; j < 16; ++j)
            wv[j] = *(const f32x4*)(wb + (size_t)j * DDIM + d0);

#pragma unroll
        for (int j = 0; j < 16; ++j) {
#pragma unroll
            for (int r = 0; r < 8; ++r) {
                acc[r][j] += xv[r].x * wv[j].x;
                acc[r][j] += xv[r].y * wv[j].y;
                acc[r][j] += xv[r].z * wv[j].z;
                acc[r][j] += xv[r].w * wv[j].w;
            }
        }
    }

    // ---- epilogue (verbatim from passing R3): fold-transpose + top-8 ----
    const float bias_l = bias[lane];

#pragma unroll
    for (int r = 0; r < 8; ++r) {
        const int gr = row0 + wid * 8 + r;

        float v[16];
#pragma unroll
        for (int j = 0; j < 16; ++j) v[j] = acc[r][j];
#pragma unroll
        for (int o = 8; o; o >>= 1) {       // fold 2o elems -> o, exchanging halves
            bool hi = (kc & o) != 0;
#pragma unroll
            for (int j = 0; j < o; ++j) {
                float send = hi ? v[j] : v[j + o];
                float keep = hi ? v[j + o] : v[j];
                v[j] = keep + __shfl_xor(send, o);
            }
        }
        float raw = v[0];                   // logit[row][expert=lane]
        float sig = 1.f / (1.f + expf(-raw));
        float vv  = raw + bias_l;

        float wsum = 0.f, myw = 0.f;
        int   myidx = 0;
#pragma unroll
        for (int k = 0; k < TOPK; ++k) {
            float m = vv;
#pragma unroll
            for (int off = 32; off; off >>= 1)
                m = fmaxf(m, __shfl_xor(m, off));
            unsigned long long b = __ballot(vv == m);
            int idx = (int)__builtin_ctzll(b);          // lowest index wins ties
            float wk = __shfl(sig, idx);
            wsum += wk;                                  // reference summation order
            if (lane == k)  { myw = wk; myidx = idx; }
            if (lane == idx) vv = -INFINITY;
        }
        if (lane < TOPK) {
            out_w[(size_t)gr * TOPK + lane] = myw / wsum;
            out_i[(size_t)gr * TOPK + lane] = (float)myidx;
        }
    }
}

extern "C" void kernel_launch(void* const* d_in, const int* in_sizes, int n_in,
                              void* d_out, int out_size, void* d_ws, size_t ws_size,
                              hipStream_t stream) {
    const float* x    = (const float*)d_in[0];
    const float* w    = (const float*)d_in[1];
    const float* bias = (const float*)d_in[2];
    const int NR = in_sizes[0] / DDIM;          // 16384 rows
    float* out   = (float*)d_out;
    float* out_w = out;
    float* out_i = out + (size_t)NR * TOPK;

    dim3 grid(NR / RB), block(BLOCK);
    hipLaunchKernelGGL(gate_kernel, grid, block, 0, stream,
                       x, w, bias, out_w, out_i);
}

// Round 9
// 103.969 us; speedup vs baseline: 1.3918x; 1.3918x over previous
//
#include <hip/hip_runtime.h>
#include <math.h>

#define BLOCK 128
#define RB 16            // rows per block -> grid = 1024 = 4 blocks/CU
#define BD 64            // K-chunk
#define NE 64
#define DDIM 2048
#define TOPK 8
#define NCHUNK (DDIM / BD)   // 32

typedef float __attribute__((ext_vector_type(4))) f32x4;

__global__ __launch_bounds__(BLOCK, 2) void gate_kernel(
    const float* __restrict__ x,      // [NR, D]
    const float* __restrict__ w,      // [E, D]
    const float* __restrict__ bias,   // [E]
    float* __restrict__ out_w,        // [NR, K]
    float* __restrict__ out_i)        // [NR, K] indices as float
{
    __shared__ float xs[2][RB * BD];   // 2 x 4 KB  (linear: global_load_lds dest)
    __shared__ float ws[2][NE * BD];   // 2 x 16 KB -> 40 KB total, 4 blocks/CU

    const int t    = threadIdx.x;
    const int lane = t & 63;
    const int wid  = t >> 6;          // 0..1; wave owns rows wid*8 .. wid*8+7
    const int kc   = lane & 15;       // col group: cols 4kc..4kc+3 of chunk
    const int kh   = lane >> 4;       // expert group: experts kh*16 .. +15
    const int row0 = blockIdx.x * RB;

    float acc[8][16];
#pragma unroll
    for (int r = 0; r < 8; ++r)
#pragma unroll
        for (int j = 0; j < 16; ++j) acc[r][j] = 0.f;

    // DMA staging, 1KB slices; per wave: 2 x-slices + 8 w-slices = 10 VMEM ops/chunk
#define ISSUE(c_, xb_, wb_)                                                    \
    {                                                                          \
        const int d0_ = (c_) * BD;                                             \
        _Pragma("unroll")                                                      \
        for (int i = 0; i < 2; ++i) {                                          \
            int s  = wid * 2 + i;                                              \
            int f  = s * 256 + lane * 4;                                       \
            int xr = f >> 6, xc = f & 63;                                      \
            __builtin_amdgcn_global_load_lds(                                  \
                (const __attribute__((address_space(1))) unsigned int*)        \
                    (x + (size_t)(row0 + xr) * DDIM + d0_ + xc),               \
                (__attribute__((address_space(3))) unsigned int*)((xb_) + s * 256), \
                16, 0, 0);                                                     \
        }                                                                      \
        _Pragma("unroll")                                                      \
        for (int i = 0; i < 8; ++i) {                                          \
            int s  = wid * 8 + i;                                              \
            int f  = s * 256 + lane * 4;                                       \
            int wr = f >> 6, wc = f & 63;                                      \
            __builtin_amdgcn_global_load_lds(                                  \
                (const __attribute__((address_space(1))) unsigned int*)        \
                    (w + (size_t)wr * DDIM + d0_ + wc),                        \
                (__attribute__((address_space(3))) unsigned int*)((wb_) + s * 256), \
                16, 0, 0);                                                     \
        }                                                                      \
    }

    ISSUE(0, xs[0], ws[0]);
    ISSUE(1, xs[1], ws[1]);

    for (int c = 0; c < NCHUNK; ++c) {
        // wait for chunk c's DMA only; chunk c+1's 10 ops stay in flight
        if (c + 1 < NCHUNK) {
            asm volatile("s_waitcnt vmcnt(10)" ::: "memory");
        } else {
            asm volatile("s_waitcnt vmcnt(0)" ::: "memory");
        }
        asm volatile("s_barrier" ::: "memory");   // all waves: chunk c resident

        const float* xsb = xs[c & 1];
        const float* wsb = ws[c & 1];

        f32x4 xv[8];
#pragma unroll
        for (int r = 0; r < 8; ++r)
            xv[r] = *(const f32x4*)&xsb[(wid * 8 + r) * BD + kc * 4];

#pragma unroll
        for (int j = 0; j < 16; ++j) {
            f32x4 wj = *(const f32x4*)&wsb[(kh * 16 + j) * BD + kc * 4];
#pragma unroll
            for (int r = 0; r < 8; ++r) {
                acc[r][j] += xv[r].x * wj.x;
                acc[r][j] += xv[r].y * wj.y;
                acc[r][j] += xv[r].z * wj.z;
                acc[r][j] += xv[r].w * wj.w;
            }
        }

        asm volatile("s_barrier" ::: "memory");   // all waves done reading buf
        if (c + 2 < NCHUNK) ISSUE(c + 2, xs[c & 1], ws[c & 1]);  // overwrite safe
    }

    // ---- epilogue (verbatim from passing R3): fold-transpose + top-8 ----
    const float bias_l = bias[lane];

#pragma unroll
    for (int r = 0; r < 8; ++r) {
        const int gr = row0 + wid * 8 + r;

        float v[16];
#pragma unroll
        for (int j = 0; j < 16; ++j) v[j] = acc[r][j];
#pragma unroll
        for (int o = 8; o; o >>= 1) {       // fold 2o elems -> o, exchanging halves
            bool hi = (kc & o) != 0;
#pragma unroll
            for (int j = 0; j < o; ++j) {
                float send = hi ? v[j] : v[j + o];
                float keep = hi ? v[j + o] : v[j];
                v[j] = keep + __shfl_xor(send, o);
            }
        }
        float raw = v[0];                   // logit[row][expert=lane]
        float sig = 1.f / (1.f + expf(-raw));
        float vv  = raw + bias_l;

        float wsum = 0.f, myw = 0.f;
        int   myidx = 0;
#pragma unroll
        for (int k = 0; k < TOPK; ++k) {
            float m = vv;
#pragma unroll
            for (int off = 32; off; off >>= 1)
                m = fmaxf(m, __shfl_xor(m, off));
            unsigned long long b = __ballot(vv == m);
            int idx = (int)__builtin_ctzll(b);          // lowest index wins ties
            float wk = __shfl(sig, idx);
            wsum += wk;                                  // reference summation order
            if (lane == k)  { myw = wk; myidx = idx; }
            if (lane == idx) vv = -INFINITY;
        }
        if (lane < TOPK) {
            out_w[(size_t)gr * TOPK + lane] = myw / wsum;
            out_i[(size_t)gr * TOPK + lane] = (float)myidx;
        }
    }
}

extern "C" void kernel_launch(void* const* d_in, const int* in_sizes, int n_in,
                              void* d_out, int out_size, void* d_ws, size_t ws_size,
                              hipStream_t stream) {
    const float* x    = (const float*)d_in[0];
    const float* w    = (const float*)d_in[1];
    const float* bias = (const float*)d_in[2];
    const int NR = in_sizes[0] / DDIM;          // 16384 rows
    float* out   = (float*)d_out;
    float* out_w = out;
    float* out_i = out + (size_t)NR * TOPK;

    dim3 grid(NR / RB), block(BLOCK);
    hipLaunchKernelGGL(gate_kernel, grid, block, 0, stream,
                       x, w, bias, out_w, out_i);
}

// Round 10
// 83.504 us; speedup vs baseline: 1.7329x; 1.2451x over previous
//
#include <hip/hip_runtime.h>
#include <math.h>

#define DDIM 2048
#define NE 64
#define TOPK 8
#define RB 32            // rows per block -> grid = 512
#define KSEG 512         // per-wave K segment (4 waves split K=2048)
#define NKT (KSEG / 32)  // 16 k-tiles of 32 per wave

typedef float f32x4 __attribute__((ext_vector_type(4)));
typedef short short8 __attribute__((ext_vector_type(8)));
typedef __bf16 bf16x8 __attribute__((ext_vector_type(8)));
typedef unsigned int uint;

// ---- truncation split: f = hi + mid + lo, each exactly representable ----
// hi = trunc-bf16(f); r = f - hi (exact); mid = trunc-bf16(r); r2 exact; lo = trunc-bf16(r2)
__device__ __forceinline__ void split3(float f, short& h, short& m, short& l) {
    uint u = __builtin_bit_cast(uint, f);
    h = (short)(u >> 16);
    float r = f - __builtin_bit_cast(float, u & 0xffff0000u);
    uint ur = __builtin_bit_cast(uint, r);
    m = (short)(ur >> 16);
    float r2 = r - __builtin_bit_cast(float, ur & 0xffff0000u);
    l = (short)(__builtin_bit_cast(uint, r2) >> 16);
}

// ---- setup: w [64][2048] fp32 -> 3 bf16 planes in d_ws ----
__global__ void wsplit_kernel(const float* __restrict__ w, short* __restrict__ wh,
                              short* __restrict__ wm, short* __restrict__ wl) {
    int tid = blockIdx.x * 256 + threadIdx.x;   // 16384 threads x 8 elems = 131072
    size_t base = (size_t)tid * 8;
    short8 hs, ms, ls;
#pragma unroll
    for (int j = 0; j < 8; ++j) {
        short h, m, l;
        split3(w[base + j], h, m, l);
        hs[j] = h; ms[j] = m; ls[j] = l;
    }
    *(short8*)&wh[base] = hs;
    *(short8*)&wm[base] = ms;
    *(short8*)&wl[base] = ls;
}

__global__ __launch_bounds__(256, 2) void gate_kernel(
    const float* __restrict__ x,      // [NR, D]
    const float* __restrict__ bias,   // [E]
    const short* __restrict__ wh,     // [E, D] bf16 planes
    const short* __restrict__ wm,
    const short* __restrict__ wl,
    float* __restrict__ out_w,        // [NR, K]
    float* __restrict__ out_i)        // [NR, K] indices as float
{
    __shared__ float slab[4][RB][NE];      // 32 KB k-quarter partials
    __shared__ float logits[RB][NE + 1];   // 8.3 KB

    const int t    = threadIdx.x;
    const int lane = t & 63;
    const int wv   = t >> 6;          // wave = k-quarter
    const int rl   = lane & 15;       // row-in-tile (A) / col-in-tile (B/C)
    const int kg   = lane >> 4;       // k-group 0..3 (8 elems each)
    const int row0 = blockIdx.x * RB;
    const int kbase = wv * KSEG;

    f32x4 acc[2][4];                  // [row-tile][expert-tile], 32 VGPR
#pragma unroll
    for (int rt = 0; rt < 2; ++rt)
#pragma unroll
        for (int et = 0; et < 4; ++et) acc[rt][et] = (f32x4){0.f, 0.f, 0.f, 0.f};

    const float* xb = x + (size_t)(row0 + rl) * DDIM + kbase + kg * 8;
    const int    wo = rl * DDIM + kbase + kg * 8;   // + et*16*DDIM + ko per frag

    for (int kt = 0; kt < NKT; ++kt) {
        const int ko = kt * 32;

        // ---- A fragments: load 8 fp32/lane per row-tile, split to 3 bf16x8 ----
        bf16x8 ah[2], am[2], al[2];
#pragma unroll
        for (int rt = 0; rt < 2; ++rt) {
            const float* xp = xb + (size_t)(rt * 16) * DDIM + ko;
            f32x4 a0 = *(const f32x4*)xp;
            f32x4 a1 = *(const f32x4*)(xp + 4);
            short8 hs, ms, ls;
#pragma unroll
            for (int j = 0; j < 4; ++j) {
                short h, m, l;
                split3(a0[j], h, m, l);
                hs[j] = h; ms[j] = m; ls[j] = l;
                split3(a1[j], h, m, l);
                hs[j + 4] = h; ms[j + 4] = m; ls[j + 4] = l;
            }
            ah[rt] = __builtin_bit_cast(bf16x8, hs);
            am[rt] = __builtin_bit_cast(bf16x8, ms);
            al[rt] = __builtin_bit_cast(bf16x8, ls);
        }

        // ---- B fragments per expert-tile (from L2-resident bf16 planes) ----
#pragma unroll
        for (int et = 0; et < 4; ++et) {
            const int bofs = et * 16 * DDIM + wo + ko;
            bf16x8 bh = __builtin_bit_cast(bf16x8, *(const short8*)&wh[bofs]);
            bf16x8 bm = __builtin_bit_cast(bf16x8, *(const short8*)&wm[bofs]);
            bf16x8 bl = __builtin_bit_cast(bf16x8, *(const short8*)&wl[bofs]);
#pragma unroll
            for (int rt = 0; rt < 2; ++rt) {
                acc[rt][et] = __builtin_amdgcn_mfma_f32_16x16x32_bf16(ah[rt], bh, acc[rt][et], 0, 0, 0);
                acc[rt][et] = __builtin_amdgcn_mfma_f32_16x16x32_bf16(ah[rt], bm, acc[rt][et], 0, 0, 0);
                acc[rt][et] = __builtin_amdgcn_mfma_f32_16x16x32_bf16(am[rt], bh, acc[rt][et], 0, 0, 0);
                acc[rt][et] = __builtin_amdgcn_mfma_f32_16x16x32_bf16(am[rt], bm, acc[rt][et], 0, 0, 0);
                acc[rt][et] = __builtin_amdgcn_mfma_f32_16x16x32_bf16(ah[rt], bl, acc[rt][et], 0, 0, 0);
                acc[rt][et] = __builtin_amdgcn_mfma_f32_16x16x32_bf16(al[rt], bh, acc[rt][et], 0, 0, 0);
            }
        }
    }

    // ---- write k-quarter partials (C/D layout: row=kg*4+r, col=rl) ----
#pragma unroll
    for (int rt = 0; rt < 2; ++rt)
#pragma unroll
        for (int et = 0; et < 4; ++et)
#pragma unroll
            for (int r = 0; r < 4; ++r)
                slab[wv][rt * 16 + kg * 4 + r][et * 16 + rl] = acc[rt][et][r];
    __syncthreads();

    // ---- reduce 4 k-quarters -> logits ----
#pragma unroll
    for (int i = 0; i < 8; ++i) {
        int idx = t * 8 + i;            // 2048 = 32 rows x 64 cols
        int r = idx >> 6, cc = idx & 63;
        logits[r][cc] = slab[0][r][cc] + slab[1][r][cc] + slab[2][r][cc] + slab[3][r][cc];
    }
    __syncthreads();

    // ---- top-8 per row, wave-parallel, lane = expert (proven exact code) ----
    const float bias_l = bias[lane];
    for (int r8 = 0; r8 < 8; ++r8) {
        const int r  = wv * 8 + r8;
        const int gr = row0 + r;
        float raw = logits[r][lane];
        float sig = 1.f / (1.f + expf(-raw));
        float vv  = raw + bias_l;

        float wsum = 0.f, myw = 0.f;
        int   myidx = 0;
#pragma unroll
        for (int k = 0; k < TOPK; ++k) {
            float m = vv;
#pragma unroll
            for (int off = 32; off; off >>= 1)
                m = fmaxf(m, __shfl_xor(m, off));
            unsigned long long b = __ballot(vv == m);
            int idx = (int)__builtin_ctzll(b);          // lowest index wins ties
            float wk = __shfl(sig, idx);
            wsum += wk;                                  // reference summation order
            if (lane == k)  { myw = wk; myidx = idx; }
            if (lane == idx) vv = -INFINITY;
        }
        if (lane < TOPK) {
            out_w[(size_t)gr * TOPK + lane] = myw / wsum;
            out_i[(size_t)gr * TOPK + lane] = (float)myidx;
        }
    }
}

extern "C" void kernel_launch(void* const* d_in, const int* in_sizes, int n_in,
                              void* d_out, int out_size, void* d_ws, size_t ws_size,
                              hipStream_t stream) {
    const float* x    = (const float*)d_in[0];
    const float* w    = (const float*)d_in[1];
    const float* bias = (const float*)d_in[2];
    const int NR = in_sizes[0] / DDIM;          // 16384 rows
    float* out   = (float*)d_out;
    float* out_w = out;
    float* out_i = out + (size_t)NR * TOPK;

    short* wh = (short*)d_ws;                   // 3 x 256 KB bf16 planes
    short* wm = wh + (size_t)NE * DDIM;
    short* wl = wm + (size_t)NE * DDIM;

    hipLaunchKernelGGL(wsplit_kernel, dim3(NE * DDIM / (256 * 8)), dim3(256), 0, stream,
                       w, wh, wm, wl);
    hipLaunchKernelGGL(gate_kernel, dim3(NR / RB), dim3(256), 0, stream,
                       x, bias, wh, wm, wl, out_w, out_i);
}